// Round 3
// baseline (38.274 us; speedup 1.0000x reference)
//
#include <hip/hip_runtime.h>

#define BLOCK 256
#define GRID  1024          // 4 blocks/CU; occupancy capped by VGPR (4 waves/SIMD)
#define UF    5             // independent int4-groups in flight per thread
#define NB_MAX 5000
#define NP_MAX 2000

__global__ __launch_bounds__(BLOCK, 4) void vs_ll_kernel(
    const float* __restrict__ v1, const float* __restrict__ v2,
    const float* __restrict__ weight,
    const float* __restrict__ e1, const float* __restrict__ e2,
    const int*  __restrict__ bidx, const int* __restrict__ pidx,
    int nb, int np, int n, float* __restrict__ partials)
{
    __shared__ float s_v1[NB_MAX];
    __shared__ float s_v2[NP_MAX];
    __shared__ float s_red[BLOCK / 64];

    // stage gather tables into LDS, vectorized (float4)
    {
        const float4* v1v = (const float4*)v1;
        const float4* v2v = (const float4*)v2;
        float4* s1v = (float4*)s_v1;
        float4* s2v = (float4*)s_v2;
        const int nb4 = nb >> 2, np4 = np >> 2;
        for (int i = threadIdx.x; i < nb4; i += BLOCK) s1v[i] = v1v[i];
        for (int i = threadIdx.x; i < np4; i += BLOCK) s2v[i] = v2v[i];
        for (int i = (nb4 << 2) + threadIdx.x; i < nb; i += BLOCK) s_v1[i] = v1[i];
        for (int i = (np4 << 2) + threadIdx.x; i < np; i += BLOCK) s_v2[i] = v2[i];
    }
    __syncthreads();

    const float w     = weight[0];
    const float onemw = 1.0f - w;
    const float LOG_LO = -13.815511f;      // log(1e-6)
    const float LOG_HI = -1.0000005e-6f;   // log(0.999999)

    float acc = 0.0f;

    const int n4 = n >> 2;
    const int T  = GRID * BLOCK;           // 262144 threads
    const int gid = blockIdx.x * BLOCK + threadIdx.x;
    const float4* e1v = (const float4*)e1;
    const float4* e2v = (const float4*)e2;
    const int4*   bv  = (const int4*)bidx;
    const int4*   pv  = (const int4*)pidx;

    // outer macro loop: each pass issues UF independent strided loads
    // (20 KB in flight per wave) before any compute -> deep MLP
    for (int base = gid; base < n4; base += UF * T) {
        float4 A[UF], C[UF];
        int4   B[UF], P[UF];
        float  msk[UF];

        #pragma unroll
        for (int k = 0; k < UF; ++k) {
            int slot = base + k * T;
            int idx  = slot < n4 ? slot : n4 - 1;   // clamp (masked later)
            msk[k] = slot < n4 ? 1.0f : 0.0f;
            A[k] = e1v[idx];
            C[k] = e2v[idx];
            B[k] = bv[idx];
            P[k] = pv[idx];
        }

        #pragma unroll
        for (int k = 0; k < UF; ++k) {
            float bb[4] = { s_v1[B[k].x], s_v1[B[k].y], s_v1[B[k].z], s_v1[B[k].w] };
            float pp[4] = { s_v2[P[k].x], s_v2[P[k].y], s_v2[P[k].z], s_v2[P[k].w] };
            float u1[4] = { A[k].x, A[k].y, A[k].z, A[k].w };
            float u2[4] = { C[k].x, C[k].y, C[k].z, C[k].w };

            float gacc = 0.0f;
            #pragma unroll
            for (int j = 0; j < 4; ++j) {
                float z  = fmaf(w, bb[j], onemw * pp[j]);
                float az = fabsf(z);
                // l = log1p(exp(-|z|)); fast math fine vs 1.6e5 abs threshold
                float l  = __logf(1.0f + __expf(-az));
                float logp = -(fmaxf(-z, 0.0f) + l);   // log(sigmoid(z))
                float logq = -(fmaxf( z, 0.0f) + l);   // log(1-sigmoid(z))
                logp = fminf(fmaxf(logp, LOG_LO), LOG_HI);
                logq = fminf(fmaxf(logq, LOG_LO), LOG_HI);
                gacc = fmaf(u1[j], logp, gacc);
                gacc = fmaf(u2[j], logq, gacc);
            }
            acc = fmaf(msk[k], gacc, acc);
        }
    }

    // scalar tail (n % 4, normally 0)
    for (int t = (n4 << 2) + gid; t < n; t += T) {
        float z  = fmaf(w, s_v1[bidx[t]], onemw * s_v2[pidx[t]]);
        float az = fabsf(z);
        float l  = __logf(1.0f + __expf(-az));
        float logp = fminf(fmaxf(-(fmaxf(-z, 0.0f) + l), LOG_LO), LOG_HI);
        float logq = fminf(fmaxf(-(fmaxf( z, 0.0f) + l), LOG_LO), LOG_HI);
        acc = fmaf(e1[t], logp, acc);
        acc = fmaf(e2[t], logq, acc);
    }

    // wave reduce (64 lanes)
    #pragma unroll
    for (int off = 32; off > 0; off >>= 1)
        acc += __shfl_down(acc, off, 64);

    const int lane = threadIdx.x & 63;
    const int wid  = threadIdx.x >> 6;
    if (lane == 0) s_red[wid] = acc;
    __syncthreads();
    if (threadIdx.x == 0) {
        float t = 0.0f;
        #pragma unroll
        for (int k = 0; k < BLOCK / 64; ++k) t += s_red[k];
        partials[blockIdx.x] = t;
    }
}

__global__ __launch_bounds__(256) void vs_reduce_kernel(
    const float* __restrict__ partials, int nparts, float* __restrict__ out)
{
    __shared__ float s_red[4];
    float acc = 0.0f;
    for (int i = threadIdx.x; i < nparts; i += 256) acc += partials[i];
    #pragma unroll
    for (int off = 32; off > 0; off >>= 1)
        acc += __shfl_down(acc, off, 64);
    const int lane = threadIdx.x & 63;
    const int wid  = threadIdx.x >> 6;
    if (lane == 0) s_red[wid] = acc;
    __syncthreads();
    if (threadIdx.x == 0) {
        float t = 0.0f;
        #pragma unroll
        for (int k = 0; k < 4; ++k) t += s_red[k];
        out[0] = t;
    }
}

extern "C" void kernel_launch(void* const* d_in, const int* in_sizes, int n_in,
                              void* d_out, int out_size, void* d_ws, size_t ws_size,
                              hipStream_t stream) {
    const float* v1     = (const float*)d_in[0];
    const float* v2     = (const float*)d_in[1];
    const float* weight = (const float*)d_in[2];
    const float* e1     = (const float*)d_in[3];
    const float* e2     = (const float*)d_in[4];
    const int*   bidx   = (const int*)d_in[5];
    const int*   pidx   = (const int*)d_in[6];

    const int nb = in_sizes[0];
    const int np = in_sizes[1];
    const int n  = in_sizes[3];

    float* partials = (float*)d_ws;
    float* out      = (float*)d_out;

    vs_ll_kernel<<<GRID, BLOCK, 0, stream>>>(v1, v2, weight, e1, e2, bidx, pidx,
                                             nb, np, n, partials);
    vs_reduce_kernel<<<1, 256, 0, stream>>>(partials, GRID, out);
}

// Round 4
// 32.605 us; speedup vs baseline: 1.1739x; 1.1739x over previous
//
#include <hip/hip_runtime.h>

#define BLOCK 256
#define GRID  512            // 2 blocks/CU (LDS-limited: 60.8 KB/block)
#define NB 5000
#define NP 2000
#define TILE 256             // float4-groups per tile (1 group = 4 pairs per thread)

// async global->LDS, 16B per lane; LDS dest must be wave-uniform base (+lane*16 in HW)
__device__ __forceinline__ void glds16(const void* g, void* l) {
    __builtin_amdgcn_global_load_lds(
        (const __attribute__((address_space(1))) unsigned int*)g,
        (__attribute__((address_space(3))) unsigned int*)l,
        16, 0, 0);
}

__global__ __launch_bounds__(BLOCK) void vs_ll_kernel(
    const float* __restrict__ v1, const float* __restrict__ v2,
    const float* __restrict__ weight,
    const float* __restrict__ e1, const float* __restrict__ e2,
    const int*  __restrict__ bidx, const int* __restrict__ pidx,
    int nb, int np, int n, float* __restrict__ partials)
{
    __shared__ float s_v1[NB];
    __shared__ float s_v2[NP];
    __shared__ float s_e1[2][TILE * 4];
    __shared__ float s_e2[2][TILE * 4];
    __shared__ int   s_bi[2][TILE * 4];
    __shared__ int   s_pi[2][TILE * 4];
    __shared__ float s_red[BLOCK / 64];

    const int tid  = threadIdx.x;
    const int wid  = tid >> 6;

    // stage gather tables into LDS, vectorized
    {
        const float4* v1v = (const float4*)v1;
        const float4* v2v = (const float4*)v2;
        float4* s1v = (float4*)s_v1;
        float4* s2v = (float4*)s_v2;
        const int nb4 = nb >> 2, np4 = np >> 2;
        for (int i = tid; i < nb4; i += BLOCK) s1v[i] = v1v[i];
        for (int i = tid; i < np4; i += BLOCK) s2v[i] = v2v[i];
        for (int i = (nb4 << 2) + tid; i < nb; i += BLOCK) s_v1[i] = v1[i];
        for (int i = (np4 << 2) + tid; i < np; i += BLOCK) s_v2[i] = v2[i];
    }

    const float w     = weight[0];
    const float onemw = 1.0f - w;
    const float LOG_LO = -13.815511f;      // log(1e-6)
    const float LOG_HI = -1.0000005e-6f;   // log(0.999999)

    const int n4 = n >> 2;                 // 2.5M float4-groups (n divisible by 4)
    const int NT = (n4 + TILE - 1) / TILE; // total tiles

    // per-wave LDS dest base for this wave's 1KB chunk of each buffer
    const int woff = wid * 64 * 4;         // element offset (64 lanes * 4 elems)

    // issue the 4 async stream loads for tile tl into buffer c (4 glds/wave)
    auto issue_tile = [&](int tl, int c) {
        int g  = tl * TILE + tid;
        int gc = g < n4 ? g : n4 - 1;      // clamp OOB lanes (masked in compute)
        glds16(e1 + (size_t)gc * 4,   &s_e1[c][woff]);
        glds16(e2 + (size_t)gc * 4,   &s_e2[c][woff]);
        glds16(bidx + (size_t)gc * 4, &s_bi[c][woff]);
        glds16(pidx + (size_t)gc * 4, &s_pi[c][woff]);
    };

    float acc = 0.0f;
    int tl = blockIdx.x;
    if (tl < NT) issue_tile(tl, 0);
    __syncthreads();   // tables visible; one-time full drain (tile0 landed too)

    int cur = 0;
    for (; tl < NT; tl += GRID, cur ^= 1) {
        const int  tnext    = tl + GRID;
        const bool has_next = tnext < NT;
        if (has_next) {
            issue_tile(tnext, cur ^ 1);
            asm volatile("s_waitcnt vmcnt(4)" ::: "memory"); // tile tl's 4 glds done
        } else {
            asm volatile("s_waitcnt vmcnt(0)" ::: "memory");
        }
        __builtin_amdgcn_s_barrier();      // all waves' tile-tl data visible

        // compute this thread's group (4 pairs) from LDS
        {
            const int g = tl * TILE + tid;
            float4 A = ((const float4*)s_e1[cur])[tid];
            float4 C = ((const float4*)s_e2[cur])[tid];
            int4   B = ((const int4*)s_bi[cur])[tid];
            int4   P = ((const int4*)s_pi[cur])[tid];

            float bb[4] = { s_v1[B.x], s_v1[B.y], s_v1[B.z], s_v1[B.w] };
            float pp[4] = { s_v2[P.x], s_v2[P.y], s_v2[P.z], s_v2[P.w] };
            float u1[4] = { A.x, A.y, A.z, A.w };
            float u2[4] = { C.x, C.y, C.z, C.w };

            float gacc = 0.0f;
            #pragma unroll
            for (int j = 0; j < 4; ++j) {
                float z  = fmaf(w, bb[j], onemw * pp[j]);
                float az = fabsf(z);
                // l = log1p(exp(-|z|)); fast math fine vs 1.6e5 abs threshold
                float l  = __logf(1.0f + __expf(-az));
                float logp = -(fmaxf(-z, 0.0f) + l);   // log(sigmoid(z))
                float logq = -(fmaxf( z, 0.0f) + l);   // log(1-sigmoid(z))
                logp = fminf(fmaxf(logp, LOG_LO), LOG_HI);
                logq = fminf(fmaxf(logq, LOG_LO), LOG_HI);
                gacc = fmaf(u1[j], logp, gacc);
                gacc = fmaf(u2[j], logq, gacc);
            }
            acc += (g < n4) ? gacc : 0.0f;
        }

        __builtin_amdgcn_s_barrier();      // protect buf[cur] before overwrite issue
    }

    // wave reduce (64 lanes)
    #pragma unroll
    for (int off = 32; off > 0; off >>= 1)
        acc += __shfl_down(acc, off, 64);

    const int lane = tid & 63;
    if (lane == 0) s_red[wid] = acc;
    __syncthreads();
    if (tid == 0) {
        float t = 0.0f;
        #pragma unroll
        for (int k = 0; k < BLOCK / 64; ++k) t += s_red[k];
        partials[blockIdx.x] = t;
    }
}

__global__ __launch_bounds__(256) void vs_reduce_kernel(
    const float* __restrict__ partials, int nparts, float* __restrict__ out)
{
    __shared__ float s_red[4];
    float acc = 0.0f;
    for (int i = threadIdx.x; i < nparts; i += 256) acc += partials[i];
    #pragma unroll
    for (int off = 32; off > 0; off >>= 1)
        acc += __shfl_down(acc, off, 64);
    const int lane = threadIdx.x & 63;
    const int wid  = threadIdx.x >> 6;
    if (lane == 0) s_red[wid] = acc;
    __syncthreads();
    if (threadIdx.x == 0) {
        float t = 0.0f;
        #pragma unroll
        for (int k = 0; k < 4; ++k) t += s_red[k];
        out[0] = t;
    }
}

extern "C" void kernel_launch(void* const* d_in, const int* in_sizes, int n_in,
                              void* d_out, int out_size, void* d_ws, size_t ws_size,
                              hipStream_t stream) {
    const float* v1     = (const float*)d_in[0];
    const float* v2     = (const float*)d_in[1];
    const float* weight = (const float*)d_in[2];
    const float* e1     = (const float*)d_in[3];
    const float* e2     = (const float*)d_in[4];
    const int*   bidx   = (const int*)d_in[5];
    const int*   pidx   = (const int*)d_in[6];

    const int nb = in_sizes[0];
    const int np = in_sizes[1];
    const int n  = in_sizes[3];

    float* partials = (float*)d_ws;
    float* out      = (float*)d_out;

    vs_ll_kernel<<<GRID, BLOCK, 0, stream>>>(v1, v2, weight, e1, e2, bidx, pidx,
                                             nb, np, n, partials);
    vs_reduce_kernel<<<1, 256, 0, stream>>>(partials, GRID, out);
}